// Round 6
// baseline (19.040 us; speedup 1.0000x reference)
//
#include <hip/hip_runtime.h>
#include <math.h>

// B=32, S=1024, D=256, V=50000.
// loss(b,s) = log S(k) - 0.98*k - 0.1*dot - 344.3348757
//   k = ||preds[b,:,s]||, dot = <emb[target], preds[b,:,s]>
//   S = 0F1(;128;k^2/4) = 1 + sum_{j>=1} prod_{i<j} (k^2/4)/((i+1)(128+i))
// (exact rewrite of -logcmk(256,k) - 0.1 dot + 0.02 k; verified absmax 0.0)
// out = sum(loss*mask)/sum(mask), mask = target != 1.

constexpr int Dc = 256;
constexpr int Sc = 1024;
constexpr int Bc = 32;
constexpr int TILE  = 64;                 // positions per tile
constexpr int NTILE = Bc * Sc / TILE;     // 512 tiles
constexpr int NBLK  = NTILE / 2;          // 256 blocks, 2 tiles each
constexpr int NW    = 8;                  // waves per block (512 threads)

using f4 = __attribute__((ext_vector_type(4))) float;

__global__ __launch_bounds__(512) void nllvmf_main(
    const float* __restrict__ preds,
    const float* __restrict__ emb,
    const int*   __restrict__ target,
    float*       __restrict__ partial)    // [0..NTILE): loss, [NTILE..2N): mask
{
    __shared__ float s_r[2][NW][2][64];   // [tile][wave][n2|dot][pos]

    const int tid = threadIdx.x;
    const int blk = blockIdx.x;
    const int g0  = blk * 2;              // tile A; tile B = g0 + 1 (same b-row)
    const int b   = g0 >> 4;
    const int s0A = (g0 & 15) * TILE;
    const int s0B = s0A + TILE;
    const int w   = tid >> 6;             // wave: dim slice w*32 .. w*32+31
    const int l   = tid & 63;
    const int td  = l >> 3;               // 8 dim-groups of 4 dims
    const int sg  = l & 7;                // 8 position-groups of 8
    const int d0  = w * 32 + td * 4;

    // targets for this thread's 16 positions (4 int4 loads, issued first)
    const int* tb = target + b * Sc;
    const int4 tA0 = *reinterpret_cast<const int4*>(tb + s0A + sg * 8);
    const int4 tA1 = *reinterpret_cast<const int4*>(tb + s0A + sg * 8 + 4);
    const int4 tB0 = *reinterpret_cast<const int4*>(tb + s0B + sg * 8);
    const int4 tB1 = *reinterpret_cast<const int4*>(tb + s0B + sg * 8 + 4);
    const int tgA[8] = {tA0.x, tA0.y, tA0.z, tA0.w, tA1.x, tA1.y, tA1.z, tA1.w};
    const int tgB[8] = {tB0.x, tB0.y, tB0.z, tB0.w, tB1.x, tB1.y, tB1.z, tB1.w};

    // 16 coalesced preds float4 (both tiles, issued up front)
    const float* pb = preds + (size_t)b * Dc * Sc + (size_t)d0 * Sc;
    f4 pA[4][2], pB[4][2];
    #pragma unroll
    for (int q = 0; q < 4; ++q) {
        pA[q][0] = *reinterpret_cast<const f4*>(pb + (size_t)q * Sc + s0A + sg * 8);
        pA[q][1] = *reinterpret_cast<const f4*>(pb + (size_t)q * Sc + s0A + sg * 8 + 4);
        pB[q][0] = *reinterpret_cast<const f4*>(pb + (size_t)q * Sc + s0B + sg * 8);
        pB[q][1] = *reinterpret_cast<const f4*>(pb + (size_t)q * Sc + s0B + sg * 8 + 4);
    }
    // 16 emb gathers (dependent only on the int4s above)
    f4 eA[8], eB[8];
    #pragma unroll
    for (int j = 0; j < 8; ++j) {
        eA[j] = *reinterpret_cast<const f4*>(emb + (size_t)tgA[j] * Dc + d0);
        eB[j] = *reinterpret_cast<const f4*>(emb + (size_t)tgB[j] * Dc + d0);
    }

    // ---- tile A compute (overlaps tile B traffic) ----
    float n2[8] = {0,0,0,0,0,0,0,0};
    float dt[8] = {0,0,0,0,0,0,0,0};
    #pragma unroll
    for (int q = 0; q < 4; ++q)
        #pragma unroll
        for (int j = 0; j < 8; ++j) {
            const float pv = pA[q][j >> 2][j & 3];
            n2[j] = fmaf(pv, pv, n2[j]);
            dt[j] = fmaf(pv, eA[j][q], dt[j]);
        }
    #pragma unroll
    for (int m = 8; m <= 32; m <<= 1)
        #pragma unroll
        for (int j = 0; j < 8; ++j) {
            n2[j] += __shfl_xor(n2[j], m, 64);
            dt[j] += __shfl_xor(dt[j], m, 64);
        }
    if (td == 0) {
        #pragma unroll
        for (int j = 0; j < 8; ++j) {
            s_r[0][w][0][sg * 8 + j] = n2[j];
            s_r[0][w][1][sg * 8 + j] = dt[j];
        }
    }

    // ---- tile B compute ----
    float n2b[8] = {0,0,0,0,0,0,0,0};
    float dtb[8] = {0,0,0,0,0,0,0,0};
    #pragma unroll
    for (int q = 0; q < 4; ++q)
        #pragma unroll
        for (int j = 0; j < 8; ++j) {
            const float pv = pB[q][j >> 2][j & 3];
            n2b[j] = fmaf(pv, pv, n2b[j]);
            dtb[j] = fmaf(pv, eB[j][q], dtb[j]);
        }
    #pragma unroll
    for (int m = 8; m <= 32; m <<= 1)
        #pragma unroll
        for (int j = 0; j < 8; ++j) {
            n2b[j] += __shfl_xor(n2b[j], m, 64);
            dtb[j] += __shfl_xor(dtb[j], m, 64);
        }
    if (td == 0) {
        #pragma unroll
        for (int j = 0; j < 8; ++j) {
            s_r[1][w][0][sg * 8 + j] = n2b[j];
            s_r[1][w][1][sg * 8 + j] = dtb[j];
        }
    }
    __syncthreads();

    // ---- tails: wave 0 -> tile A, wave 1 -> tile B ----
    if (tid < 128) {
        const int t   = tid >> 6;         // which tile
        const int pos = tid & 63;
        float norm2 = 0.f, dot = 0.f;
        #pragma unroll
        for (int w2 = 0; w2 < NW; ++w2) {
            norm2 += s_r[t][w2][0][pos];
            dot   += s_r[t][w2][1][pos];
        }
        const int tgt = target[b * Sc + s0A + t * TILE + pos];

        const float k = sqrtf(norm2);
        const float r = 0.25f * norm2;

        // S = 0F1(;128;r), 32-term recurrence; reciprocals are literals
        constexpr float INV[32] = {
            1.0f/128.0f,  1.0f/258.0f,  1.0f/390.0f,  1.0f/524.0f,
            1.0f/660.0f,  1.0f/798.0f,  1.0f/938.0f,  1.0f/1080.0f,
            1.0f/1224.0f, 1.0f/1370.0f, 1.0f/1518.0f, 1.0f/1668.0f,
            1.0f/1820.0f, 1.0f/1974.0f, 1.0f/2130.0f, 1.0f/2288.0f,
            1.0f/2448.0f, 1.0f/2610.0f, 1.0f/2774.0f, 1.0f/2940.0f,
            1.0f/3108.0f, 1.0f/3278.0f, 1.0f/3450.0f, 1.0f/3624.0f,
            1.0f/3800.0f, 1.0f/3978.0f, 1.0f/4158.0f, 1.0f/4340.0f,
            1.0f/4524.0f, 1.0f/4710.0f, 1.0f/4898.0f, 1.0f/5088.0f };
        float tt = 1.0f, S = 1.0f;
        #pragma unroll
        for (int j = 0; j < 32; ++j) { tt *= r * INV[j]; S += tt; }

        float loss = __logf(S) - 0.98f * k - 0.1f * dot - 344.3348757f;
        float msk  = (tgt != 1) ? 1.0f : 0.0f;
        loss *= msk;

        #pragma unroll
        for (int m = 32; m; m >>= 1) {
            loss += __shfl_xor(loss, m, 64);
            msk  += __shfl_xor(msk,  m, 64);
        }
        if (pos == 0) {
            partial[g0 + t]         = loss;
            partial[NTILE + g0 + t] = msk;
        }
    }
}

__global__ __launch_bounds__(256) void nllvmf_finalize(
    const float* __restrict__ partial, float* __restrict__ out)
{
    __shared__ float sl[4], sm[4];
    const int tid = threadIdx.x;
    float l = 0.f, m = 0.f;
    for (int i = tid; i < NTILE; i += 256) {
        l += partial[i];
        m += partial[NTILE + i];
    }
    #pragma unroll
    for (int off = 32; off; off >>= 1) {
        l += __shfl_down(l, off, 64);
        m += __shfl_down(m, off, 64);
    }
    if ((tid & 63) == 0) { sl[tid >> 6] = l; sm[tid >> 6] = m; }
    __syncthreads();
    if (tid == 0)
        out[0] = (sl[0] + sl[1] + sl[2] + sl[3]) / (sm[0] + sm[1] + sm[2] + sm[3]);
}

extern "C" void kernel_launch(void* const* d_in, const int* in_sizes, int n_in,
                              void* d_out, int out_size, void* d_ws, size_t ws_size,
                              hipStream_t stream) {
    const float* preds  = (const float*)d_in[0];
    const float* emb    = (const float*)d_in[1];
    const int*   target = (const int*)d_in[2];
    float* out = (float*)d_out;
    float* ws  = (float*)d_ws;

    nllvmf_main<<<NBLK, 512, 0, stream>>>(preds, emb, target, ws);
    nllvmf_finalize<<<1, 256, 0, stream>>>(ws, out);
}

// Round 7
// 17.953 us; speedup vs baseline: 1.0605x; 1.0605x over previous
//
#include <hip/hip_runtime.h>
#include <math.h>

// B=32, S=1024, D=256, V=50000.
// loss(b,s) = log S(k) - 0.98*k - 0.1*dot - 344.3348757
//   k = ||preds[b,:,s]||, dot = <emb[target], preds[b,:,s]>
//   S = 0F1(;128;k^2/4) = 1 + sum_{j>=1} prod_{i<j} (k^2/4)/((i+1)(128+i))
// (exact rewrite of -logcmk(256,k) - 0.1 dot + 0.02 k; verified absmax 0.0)
// out = sum(loss*mask)/sum(mask), mask = target != 1.

constexpr int Dc = 256;
constexpr int Sc = 1024;
constexpr int Bc = 32;
constexpr int TILE = 64;                  // positions per block
constexpr int NBLK = Bc * Sc / TILE;      // 512
constexpr int NW   = 8;                   // waves per block (512 threads)

using f4 = __attribute__((ext_vector_type(4))) float;

__global__ __launch_bounds__(512, 4) void nllvmf_main(
    const float* __restrict__ preds,
    const float* __restrict__ emb,
    const int*   __restrict__ target,
    float*       __restrict__ partial)    // [0..NBLK): loss, [NBLK..2N): mask
{
    __shared__ float s_r[NW][2][64];      // [wave][n2|dot][pos]

    const int tid = threadIdx.x;
    const int blk = blockIdx.x;
    const int b   = blk >> 4;             // Sc/TILE = 16 blocks per batch row
    const int s0  = (blk & 15) * TILE;
    const int w   = tid >> 6;             // wave: dim slice w*32 .. w*32+31
    const int l   = tid & 63;
    const int td  = l >> 3;               // 8 dim-groups of 4 dims
    const int sg  = l & 7;                // 8 position-groups
    const int d0  = w * 32 + td * 4;
    const int p0  = s0 + sg * 4;          // chunk c=0: p0..p0+3, c=1: p0+32..p0+35

    // targets for this thread's 8 positions (two int4, both 16B-aligned)
    const int4 tA = *reinterpret_cast<const int4*>(target + b * Sc + p0);
    const int4 tB = *reinterpret_cast<const int4*>(target + b * Sc + p0 + 32);
    const int tg[8] = {tA.x, tA.y, tA.z, tA.w, tB.x, tB.y, tB.z, tB.w};

    // 8 preds float4, non-temporal (read-once stream; don't pollute L2/L3).
    // Per td-group each instruction covers 128B fully-contiguous, fully used.
    const float* pb = preds + (size_t)b * Dc * Sc + (size_t)d0 * Sc + p0;
    f4 p[4][2];
    #pragma unroll
    for (int q = 0; q < 4; ++q) {
        p[q][0] = __builtin_nontemporal_load(reinterpret_cast<const f4*>(pb + (size_t)q * Sc));
        p[q][1] = __builtin_nontemporal_load(reinterpret_cast<const f4*>(pb + (size_t)q * Sc + 32));
    }
    // 8 emb gathers (normal loads -> L2/L3 resident across replays)
    f4 e[8];
    #pragma unroll
    for (int j = 0; j < 8; ++j)
        e[j] = *reinterpret_cast<const f4*>(emb + (size_t)tg[j] * Dc + d0);

    float n2[8] = {0,0,0,0,0,0,0,0};
    float dt[8] = {0,0,0,0,0,0,0,0};
    #pragma unroll
    for (int q = 0; q < 4; ++q)
        #pragma unroll
        for (int j = 0; j < 8; ++j) {
            const float pv = p[q][j >> 2][j & 3];
            n2[j] = fmaf(pv, pv, n2[j]);
            dt[j] = fmaf(pv, e[j][q], dt[j]);
        }

    // butterfly over td (lane bits 3..5): sum this wave's 32 dims
    #pragma unroll
    for (int m = 8; m <= 32; m <<= 1)
        #pragma unroll
        for (int j = 0; j < 8; ++j) {
            n2[j] += __shfl_xor(n2[j], m, 64);
            dt[j] += __shfl_xor(dt[j], m, 64);
        }

    if (td == 0) {
        #pragma unroll
        for (int j = 0; j < 8; ++j) {
            const int pos = (j >> 2) * 32 + sg * 4 + (j & 3);
            s_r[w][0][pos] = n2[j];
            s_r[w][1][pos] = dt[j];
        }
    }
    __syncthreads();

    if (tid < 64) {
        float norm2 = 0.f, dot = 0.f;
        #pragma unroll
        for (int w2 = 0; w2 < NW; ++w2) {
            norm2 += s_r[w2][0][tid];
            dot   += s_r[w2][1][tid];
        }
        const int tgt = target[b * Sc + s0 + tid];

        const float k = sqrtf(norm2);
        const float r = 0.25f * norm2;

        // S = 0F1(;128;r), 32-term recurrence; reciprocals are literals
        constexpr float INV[32] = {
            1.0f/128.0f,  1.0f/258.0f,  1.0f/390.0f,  1.0f/524.0f,
            1.0f/660.0f,  1.0f/798.0f,  1.0f/938.0f,  1.0f/1080.0f,
            1.0f/1224.0f, 1.0f/1370.0f, 1.0f/1518.0f, 1.0f/1668.0f,
            1.0f/1820.0f, 1.0f/1974.0f, 1.0f/2130.0f, 1.0f/2288.0f,
            1.0f/2448.0f, 1.0f/2610.0f, 1.0f/2774.0f, 1.0f/2940.0f,
            1.0f/3108.0f, 1.0f/3278.0f, 1.0f/3450.0f, 1.0f/3624.0f,
            1.0f/3800.0f, 1.0f/3978.0f, 1.0f/4158.0f, 1.0f/4340.0f,
            1.0f/4524.0f, 1.0f/4710.0f, 1.0f/4898.0f, 1.0f/5088.0f };
        float t = 1.0f, S = 1.0f;
        #pragma unroll
        for (int j = 0; j < 32; ++j) { t *= r * INV[j]; S += t; }

        float loss = __logf(S) - 0.98f * k - 0.1f * dot - 344.3348757f;
        float msk  = (tgt != 1) ? 1.0f : 0.0f;
        loss *= msk;

        #pragma unroll
        for (int m = 32; m; m >>= 1) {
            loss += __shfl_xor(loss, m, 64);
            msk  += __shfl_xor(msk,  m, 64);
        }
        if (tid == 0) {
            partial[blk]        = loss;
            partial[NBLK + blk] = msk;
        }
    }
}

__global__ __launch_bounds__(128) void nllvmf_finalize(
    const float* __restrict__ partial, float* __restrict__ out)
{
    __shared__ float sl[2], sm[2];
    const int tid = threadIdx.x;
    // 128 threads x one float4 from each array: covers 512 floats each
    f4 lv = *reinterpret_cast<const f4*>(partial + tid * 4);
    f4 mv = *reinterpret_cast<const f4*>(partial + NBLK + tid * 4);
    float l = lv.x + lv.y + lv.z + lv.w;
    float m = mv.x + mv.y + mv.z + mv.w;
    #pragma unroll
    for (int off = 32; off; off >>= 1) {
        l += __shfl_down(l, off, 64);
        m += __shfl_down(m, off, 64);
    }
    if ((tid & 63) == 0) { sl[tid >> 6] = l; sm[tid >> 6] = m; }
    __syncthreads();
    if (tid == 0)
        out[0] = (sl[0] + sl[1]) / (sm[0] + sm[1]);
}

extern "C" void kernel_launch(void* const* d_in, const int* in_sizes, int n_in,
                              void* d_out, int out_size, void* d_ws, size_t ws_size,
                              hipStream_t stream) {
    const float* preds  = (const float*)d_in[0];
    const float* emb    = (const float*)d_in[1];
    const int*   target = (const int*)d_in[2];
    float* out = (float*)d_out;
    float* ws  = (float*)d_ws;

    nllvmf_main<<<NBLK, 512, 0, stream>>>(preds, emb, target, ws);
    nllvmf_finalize<<<1, 128, 0, stream>>>(ws, out);
}